// Round 15
// baseline (869.494 us; speedup 1.0000x reference)
//
#include <hip/hip_runtime.h>

typedef _Float16 f16x8 __attribute__((ext_vector_type(8)));
typedef float f32x4 __attribute__((ext_vector_type(4)));

#define BIGF 1e30f
#define M_TOT 32768
#define H2 2048

// ---- ws layout (bytes) ----
#define WS_XH 0u                     // 32768*1024 f16 = 67108864
#define WS_WT 67108864u              // 4096*1024 f16  = 8388608
#define WS_BVEC 75497472u            // 4096 f32
#define WS_GW2 75513856u             // 4096 f32
#define WS_CONSTS 75530240u          // 4 f32 (C1s,C2s,C1e,C2e)
#define WS_PART 75530496u            // 16*3*32768 f32 = 6291456
#define WS_TPART 100696320u          // 8*8*6 f32

// ---------------- merged prep: X cvt (16384 blk) + W cvt (1024 blk) + vec/const prep (18 blk) ----
__global__ void k_pre(const float* __restrict__ x, _Float16* __restrict__ xh,
                      const float* __restrict__ w_s, const float* __restrict__ w_e,
                      _Float16* __restrict__ wt,
                      const float* __restrict__ s_b1, const float* __restrict__ s_g,
                      const float* __restrict__ s_w2, const float* __restrict__ s_b,
                      const float* __restrict__ s_b2, const float* __restrict__ e_b1,
                      const float* __restrict__ e_g, const float* __restrict__ e_w2,
                      const float* __restrict__ e_b, const float* __restrict__ e_b2,
                      float* __restrict__ bvec, float* __restrict__ gw2,
                      float* __restrict__ consts) {
  __shared__ float tile[64][65];
  int bid = blockIdx.x;
  if (bid < 16384) {
    size_t i = ((size_t)bid * 256 + threadIdx.x) * 8;
    float4 v0 = *(const float4*)(x + i);
    float4 v1 = *(const float4*)(x + i + 4);
    f16x8 h;
    h[0] = (_Float16)v0.x; h[1] = (_Float16)v0.y; h[2] = (_Float16)v0.z; h[3] = (_Float16)v0.w;
    h[4] = (_Float16)v1.x; h[5] = (_Float16)v1.y; h[6] = (_Float16)v1.z; h[7] = (_Float16)v1.w;
    *(f16x8*)(xh + i) = h;
  } else if (bid < 17408) {
    int r = bid - 16384;
    int bx = r & 31, by = (r >> 5) & 15, bz = r >> 9;
    const float* w = bz ? w_e : w_s;
    int n0 = bx * 64, k0 = by * 64;
    int tx = threadIdx.x & 63, ty = threadIdx.x >> 6;
#pragma unroll
    for (int i = ty; i < 64; i += 4) tile[i][tx] = w[(size_t)(k0 + i) * H2 + n0 + tx];
    __syncthreads();
#pragma unroll
    for (int i = ty; i < 64; i += 4)
      wt[((size_t)(bz * H2 + n0 + i)) * 1024 + k0 + tx] = (_Float16)tile[tx][i];
  } else {
    int blk = bid - 17408;
    if (blk < 16) {
      int i = blk * 256 + threadIdx.x;
      int head = i >> 11, j = i & (H2 - 1);
      bvec[i] = head ? e_b1[j] : s_b1[j];
      gw2[i] = head ? e_g[j] * e_w2[j] : s_g[j] * s_w2[j];
    } else {
      int h = blk - 16;
      const float* g = h ? e_g : s_g;
      const float* b = h ? e_b : s_b;
      const float* w2 = h ? e_w2 : s_w2;
      const float* b2 = h ? e_b2 : s_b2;
      float c1 = 0.f, c2 = 0.f;
      for (int j = threadIdx.x; j < H2; j += 256) {
        float w = w2[j];
        c1 += g[j] * w;
        c2 += b[j] * w;
      }
      for (int m = 1; m < 64; m <<= 1) { c1 += __shfl_xor(c1, m); c2 += __shfl_xor(c2, m); }
      __shared__ float r1[4], r2[4];
      int wid = threadIdx.x >> 6;
      if ((threadIdx.x & 63) == 0) { r1[wid] = c1; r2[wid] = c2; }
      __syncthreads();
      if (threadIdx.x == 0) {
        consts[h * 2 + 0] = r1[0] + r1[1] + r1[2] + r1[3];
        consts[h * 2 + 1] = r2[0] + r2[1] + r2[2] + r2[3] + b2[0];
      }
    }
  }
}

// ---------------- fused GEMM: [32768,1024] x [1024,4096], relu+LN-reduction epilogue ----
// BM=BN=256, BK=64, 512 threads = 8 waves (2M x 4N), wave tile 128x64, acc[8][4],
// mfma_f32_16x16x32_f16, LDS 2 x 64KB XOR-swizzled.
// BALANCED 4/8/4/8 phase loads + PHASE-EARLY issue (round-4 x round-9 hybrid):
// phases = (m-half, k-half). Each phase: issue next phase's frags (4 or 8 ds_read);
// counted lgkm retires previous phase's frags; barrier; 16 MFMA on frags issued one
// phase ago. Staging post-barrier into regions whose reads retired (ledger below);
// vmcnt(0) once per tile at ph2 (ops are a full tile old -> no stall).
#define BUF 65536
#define STA(q, tile, bufo)                                                              \
  __builtin_amdgcn_global_load_lds(                                                     \
      (const __attribute__((address_space(1))) unsigned int*)(srcA + (size_t)(q) * 131072 + (size_t)(tile) * 128), \
      (__attribute__((address_space(3))) unsigned int*)(lds + (bufo) + (q) * 8192 + t * 16), 16, 0, 0)
#define STB(q, tile, bufo)                                                              \
  __builtin_amdgcn_global_load_lds(                                                     \
      (const __attribute__((address_space(1))) unsigned int*)(srcB + (size_t)(q) * 131072 + (size_t)(tile) * 128), \
      (__attribute__((address_space(3))) unsigned int*)(lds + (bufo) + 32768 + (q) * 8192 + t * 16), 16, 0, 0)

#define RD_A(AF, mh, low, BUFO)                                                         \
  _Pragma("unroll")                                                                     \
  for (int mi = 0; mi < 4; ++mi)                                                        \
    AF[mi] = *(const f16x8*)(lds + (BUFO) + (unsigned)((wmg * 128 + (mh) * 64 + mi * 16 + c15) * 128) + (low));

#define RD_B(BF, low, BUFO)                                                             \
  _Pragma("unroll")                                                                     \
  for (int nj = 0; nj < 4; ++nj)                                                        \
    BF[nj] = *(const f16x8*)(lds + (BUFO) + 32768 + (unsigned)((wn + nj * 16 + c15) * 128) + (low));

#define MF16(mh, AF, BF)                                                                \
  __builtin_amdgcn_s_setprio(1);                                                        \
  _Pragma("unroll")                                                                     \
  for (int mi = 0; mi < 4; ++mi)                                                        \
    _Pragma("unroll")                                                                   \
    for (int nj = 0; nj < 4; ++nj)                                                      \
      acc[(mh) * 4 + mi][nj] =                                                          \
          __builtin_amdgcn_mfma_f32_16x16x32_f16(AF[mi], BF[nj], acc[(mh) * 4 + mi][nj], 0, 0, 0); \
  __builtin_amdgcn_s_setprio(0);

#define LGKM_BAR(N)                                                                     \
  asm volatile("s_waitcnt lgkmcnt(" #N ")" ::: "memory");                               \
  __builtin_amdgcn_s_barrier();                                                         \
  __builtin_amdgcn_sched_barrier(0);

__global__ __launch_bounds__(512, 2) void k_gemm(const _Float16* __restrict__ Xh,
                                                 const _Float16* __restrict__ Wt,
                                                 const float* __restrict__ bvec,
                                                 const float* __restrict__ gw2,
                                                 float* __restrict__ partials) {
  __shared__ char lds[2 * BUF];  // 128 KiB
  const int nb = blockIdx.x;  // 0..15   (256-col block)
  const int mb = blockIdx.y;  // 0..127  (256-row block)
  const int t = threadIdx.x;
  const int lane = t & 63, wid = t >> 6;
  const int c15 = lane & 15, g4 = lane >> 4;
  const int wmg = wid >> 2;        // 0..1 -> rows wmg*128..+128
  const int wq = wid & 3;          // 0..3 -> cols wq*64..+64
  const int wn = wq * 64;

  f32x4 acc[8][4];
#pragma unroll
  for (int i = 0; i < 8; ++i)
#pragma unroll
    for (int j = 0; j < 4; ++j) acc[i][j] = (f32x4){0.f, 0.f, 0.f, 0.f};

  // stage sources: quarter q (64 rows), thread t writes LDS bytes [t*16, t*16+16)
  const char* Abase = (const char*)(Xh + (size_t)mb * 256 * 1024);
  const char* Bbase = (const char*)(Wt + (size_t)nb * 256 * 1024);
  const int rowl = t >> 3;  // 0..63 row within quarter
  const int swz = ((t & 7) * 16) ^ ((rowl & 7) << 4);
  const char* srcA = Abase + (size_t)rowl * 2048 + swz;
  const char* srcB = Bbase + (size_t)rowl * 2048 + swz;

  // ds_read address pieces (XOR swizzle of byte-bits 4-6 within 128B rows)
  const int xorv = (c15 & 7) << 4;
  const unsigned low0 = (unsigned)((g4 * 16) ^ xorv);        // k-half 0
  const unsigned low1 = (unsigned)((64 + g4 * 16) ^ xorv);   // k-half 1

  // ---- prologue: tile0 -> buf0, tile1 -> buf1; retire tile0; preload ph0 frags ----
  STA(0, 0, 0); STA(1, 0, 0); STA(2, 0, 0); STA(3, 0, 0);
  STB(0, 0, 0); STB(1, 0, 0); STB(2, 0, 0); STB(3, 0, 0);
  STA(0, 1, BUF); STA(1, 1, BUF); STA(2, 1, BUF); STA(3, 1, BUF);
  STB(0, 1, BUF); STB(1, 1, BUF); STB(2, 1, BUF); STB(3, 1, BUF);
  asm volatile("s_waitcnt vmcnt(8)" ::: "memory");
  __builtin_amdgcn_s_barrier();
  __builtin_amdgcn_sched_barrier(0);

  f16x8 afA[4], afB[4], bfA[4], bfB[4];
  RD_A(afA, 0, low0, 0u)   // A(m0,k0)
  RD_B(bfA, low0, 0u)      // B(k0)

#pragma unroll 2
  for (int g = 0; g < 16; ++g) {
    const unsigned ob = (unsigned)(g & 1) * BUF;
    const unsigned on = ob ^ BUF;

    // ---- ph0 (m0,k0): issue A(m1,k0); retire afA,bfA (8 older); MFMA m0xk0 ----
    RD_A(afB, 1, low0, ob)
    LGKM_BAR(4)
    MF16(0, afA, bfA)
    __builtin_amdgcn_s_barrier();
    __builtin_amdgcn_sched_barrier(0);

    // ---- ph1 (m1,k0): issue A(m0,k1)+B(k1); retire afB; MFMA m1xk0 ----
    RD_A(afA, 0, low1, ob)
    RD_B(bfB, low1, ob)
    LGKM_BAR(8)
    MF16(1, afB, bfA)
    __builtin_amdgcn_s_barrier();
    __builtin_amdgcn_sched_barrier(0);

    // ---- ph2 (m0,k1): issue A(m1,k1); retire afA,bfB; vmcnt(0) retires tile g+1's
    //      staging (issued a full tile ago); barrier publishes buf on ----
    RD_A(afB, 1, low1, ob)
    asm volatile("s_waitcnt lgkmcnt(4)" ::: "memory");
    if (g < 15) asm volatile("s_waitcnt vmcnt(0)" ::: "memory");
    __builtin_amdgcn_s_barrier();
    __builtin_amdgcn_sched_barrier(0);
    // post-barrier: A(m0)@g and B@g reads all retired pre-barrier -> stage g+2 there
    if (g < 14) {
      STB(0, g + 2, ob); STB(1, g + 2, ob); STB(2, g + 2, ob); STB(3, g + 2, ob);
      STA(0, g + 2, ob); STA(1, g + 2, ob);
    }
    MF16(0, afA, bfB)
    __builtin_amdgcn_s_barrier();
    __builtin_amdgcn_sched_barrier(0);

    // ---- ph3 (m1,k1): issue next tile's A(m0,k0)+B(k0) from on; retire afB; MFMA ----
    if (g < 15) {
      RD_A(afA, 0, low0, on)
      RD_B(bfA, low0, on)
      LGKM_BAR(8)
    } else {
      LGKM_BAR(0)
    }
    // post-barrier: A(m1)@g reads retired pre-barrier -> stage its g+2 quarters
    if (g < 14) { STA(2, g + 2, ob); STA(3, g + 2, ob); }
    MF16(1, afB, bfB)
    __builtin_amdgcn_s_barrier();
    __builtin_amdgcn_sched_barrier(0);
  }

  // ---- epilogue: h = relu(acc + b1); per-lane S1,S2,S3; cross-wave reduce via LDS ----
  __syncthreads();
  float* red = (float*)lds;  // [wmg][wq][row128][3] = 12 KB

  float bv[4], gv[4];
#pragma unroll
  for (int nj = 0; nj < 4; ++nj) {
    int col = nb * 256 + wn + nj * 16 + c15;
    bv[nj] = bvec[col];
    gv[nj] = gw2[col];
  }
#pragma unroll
  for (int mi = 0; mi < 8; ++mi) {
#pragma unroll
    for (int r = 0; r < 4; ++r) {
      float s1 = 0.f, s2 = 0.f, s3 = 0.f;
#pragma unroll
      for (int nj = 0; nj < 4; ++nj) {
        float v = acc[mi][nj][r] + bv[nj];
        v = fmaxf(v, 0.f);
        s1 += v;
        s2 += v * v;
        s3 += v * gv[nj];
      }
#pragma unroll
      for (int m = 1; m < 16; m <<= 1) {
        s1 += __shfl_xor(s1, m);
        s2 += __shfl_xor(s2, m);
        s3 += __shfl_xor(s3, m);
      }
      if (c15 == 0) {
        int row = mi * 16 + g4 * 4 + r;  // 0..127 within wave-group
        float* p = red + (((wmg * 4 + wq) * 128 + row) * 3);
        p[0] = s1; p[1] = s2; p[2] = s3;
      }
    }
  }
  __syncthreads();
  // sum the 4 N-waves; write 16-slice partials
  for (int idx = t; idx < 768; idx += 512) {
    int wmgi = idx / 384;
    int rem = idx - wmgi * 384;
    int row = rem / 3, k = rem - row * 3;
    float s = red[((wmgi * 4 + 0) * 128 + row) * 3 + k] +
              red[((wmgi * 4 + 1) * 128 + row) * 3 + k] +
              red[((wmgi * 4 + 2) * 128 + row) * 3 + k] +
              red[((wmgi * 4 + 3) * 128 + row) * 3 + k];
    int rowg = mb * 256 + wmgi * 128 + row;
    partials[((size_t)(nb * 3 + k)) * M_TOT + rowg] = s;
  }
}

// ---------------- reduce partials (16 slices: 0-7 start, 8-15 end) -> preds ----------------
__global__ void k_reduce(const float* __restrict__ partials, const float* __restrict__ consts,
                         const float* __restrict__ mask, float* __restrict__ out) {
  int m = blockIdx.x * 256 + threadIdx.x;  // 0..32767
  float s1 = 0.f, s2 = 0.f, s3 = 0.f, e1 = 0.f, e2 = 0.f, e3 = 0.f;
  for (int nb = 0; nb < 8; ++nb) {
    s1 += partials[((size_t)(nb * 3 + 0)) * M_TOT + m];
    s2 += partials[((size_t)(nb * 3 + 1)) * M_TOT + m];
    s3 += partials[((size_t)(nb * 3 + 2)) * M_TOT + m];
  }
  for (int nb = 8; nb < 16; ++nb) {
    e1 += partials[((size_t)(nb * 3 + 0)) * M_TOT + m];
    e2 += partials[((size_t)(nb * 3 + 1)) * M_TOT + m];
    e3 += partials[((size_t)(nb * 3 + 2)) * M_TOT + m];
  }
  const float H = (float)H2;
  float mu = s1 / H;
  float var = fmaxf(s2 / H - mu * mu, 0.f);
  float rs = 1.f / sqrtf(var + 1e-12f);
  float score_s = rs * (s3 - mu * consts[0]) + consts[1];
  mu = e1 / H;
  var = fmaxf(e2 / H - mu * mu, 0.f);
  rs = 1.f / sqrtf(var + 1e-12f);
  float score_e = rs * (e3 - mu * consts[2]) + consts[3];
  float mk = BIGF * (1.f - mask[m]);
  out[m] = score_s - mk;
  out[M_TOT + m] = score_e - mk;
}

// ---------------- type head ----------------
__global__ void k_type_partial(const float* __restrict__ X, const float* __restrict__ w1,
                               const float* __restrict__ b1, const float* __restrict__ g,
                               const float* __restrict__ w2, float* __restrict__ tpart) {
  __shared__ float xs[1024];
  int cb = blockIdx.x, tok = blockIdx.y, t = threadIdx.x;
  const float* xp = X + (size_t)tok * 4096 * 1024;  // x[b,0,:]
  for (int i = t; i < 1024; i += 256) xs[i] = xp[i];
  __syncthreads();
  int j = cb * 256 + t;
  float dot = 0.f;
  for (int k = 0; k < 1024; ++k) dot += xs[k] * w1[(size_t)k * H2 + j];
  float h = fmaxf(dot + b1[j], 0.f);
  float gj = g[j];
  float s[6];
  s[0] = h;
  s[1] = h * h;
#pragma unroll
  for (int c = 0; c < 4; ++c) s[2 + c] = h * gj * w2[j * 4 + c];
  for (int m = 1; m < 64; m <<= 1)
#pragma unroll
    for (int q = 0; q < 6; ++q) s[q] += __shfl_xor(s[q], m);
  __shared__ float red[4][6];
  int wid = t >> 6;
  if ((t & 63) == 0)
#pragma unroll
    for (int q = 0; q < 6; ++q) red[wid][q] = s[q];
  __syncthreads();
  if (t == 0)
#pragma unroll
    for (int q = 0; q < 6; ++q)
      tpart[(tok * 8 + cb) * 6 + q] = red[0][q] + red[1][q] + red[2][q] + red[3][q];
}

__global__ void k_type_final(const float* __restrict__ tpart, const float* __restrict__ g,
                             const float* __restrict__ bb, const float* __restrict__ w2,
                             const float* __restrict__ b2, float* __restrict__ out) {
  int t = threadIdx.x;
  float c1[4] = {0.f, 0.f, 0.f, 0.f}, c2[4] = {0.f, 0.f, 0.f, 0.f};
  for (int j = t; j < H2; j += 256) {
    float gj = g[j], bj = bb[j];
#pragma unroll
    for (int c = 0; c < 4; ++c) {
      float w = w2[j * 4 + c];
      c1[c] += gj * w;
      c2[c] += bj * w;
    }
  }
  for (int m = 1; m < 64; m <<= 1)
#pragma unroll
    for (int c = 0; c < 4; ++c) { c1[c] += __shfl_xor(c1[c], m); c2[c] += __shfl_xor(c2[c], m); }
  __shared__ float rC1[4][4], rC2[4][4];
  int wid = t >> 6;
  if ((t & 63) == 0)
#pragma unroll
    for (int c = 0; c < 4; ++c) { rC1[wid][c] = c1[c]; rC2[wid][c] = c2[c]; }
  __syncthreads();
  __shared__ float sC1[4], sC2[4];
  if (t < 4) {
    sC1[t] = rC1[0][t] + rC1[1][t] + rC1[2][t] + rC1[3][t];
    sC2[t] = rC2[0][t] + rC2[1][t] + rC2[2][t] + rC2[3][t];
  }
  __syncthreads();
  if (t < 32) {
    int tok = t >> 2, c = t & 3;
    float s1 = 0.f, s2 = 0.f, s3 = 0.f;
    for (int cb = 0; cb < 8; ++cb) {
      s1 += tpart[(tok * 8 + cb) * 6 + 0];
      s2 += tpart[(tok * 8 + cb) * 6 + 1];
      s3 += tpart[(tok * 8 + cb) * 6 + 2 + c];
    }
    float mu = s1 / (float)H2;
    float var = fmaxf(s2 / (float)H2 - mu * mu, 0.f);
    float rs = 1.f / sqrtf(var + 1e-12f);
    out[65536 + tok * 4 + c] = rs * (s3 - mu * sC1[c]) + sC2[c] + b2[c];
  }
}

// ---------------- band max + argmax ----------------
__global__ void k_band(const float* __restrict__ preds, float* __restrict__ out) {
  __shared__ float ss[4096], se[4096];
  int b = blockIdx.x, t = threadIdx.x;
  for (int i = t; i < 4096; i += 256) {
    ss[i] = preds[(size_t)b * 4096 + i];
    se[i] = preds[M_TOT + (size_t)b * 4096 + i];
  }
  __syncthreads();
  float bv1 = -3.0e38f, bv2 = -3.0e38f;
  int bi1 = 0x7fffffff, bi2 = 0x7fffffff;
  for (int i = t; i < 4096; i += 256) {
    float m1 = -3.0e38f;
    int jmax = i + 15 < 4095 ? i + 15 : 4095;
    for (int j = i; j <= jmax; ++j) m1 = fmaxf(m1, se[j]);
    float v1 = ss[i] + m1;
    if (v1 > bv1 || (v1 == bv1 && i < bi1)) { bv1 = v1; bi1 = i; }
    float m2 = -3.0e38f;
    int imin = i - 15 > 0 ? i - 15 : 0;
    for (int j = imin; j <= i; ++j) m2 = fmaxf(m2, ss[j]);
    float v2 = se[i] + m2;
    if (v2 > bv2 || (v2 == bv2 && i < bi2)) { bv2 = v2; bi2 = i; }
  }
  for (int m = 1; m < 64; m <<= 1) {
    float ov = __shfl_xor(bv1, m);
    int oi = __shfl_xor(bi1, m);
    if (ov > bv1 || (ov == bv1 && oi < bi1)) { bv1 = ov; bi1 = oi; }
    ov = __shfl_xor(bv2, m);
    oi = __shfl_xor(bi2, m);
    if (ov > bv2 || (ov == bv2 && oi < bi2)) { bv2 = ov; bi2 = oi; }
  }
  __shared__ float rv[2][4];
  __shared__ int ri[2][4];
  int wid = t >> 6;
  if ((t & 63) == 0) { rv[0][wid] = bv1; ri[0][wid] = bi1; rv[1][wid] = bv2; ri[1][wid] = bi2; }
  __syncthreads();
  if (t == 0) {
    float v = rv[0][0];
    int ix = ri[0][0];
    for (int w = 1; w < 4; ++w)
      if (rv[0][w] > v || (rv[0][w] == v && ri[0][w] < ix)) { v = rv[0][w]; ix = ri[0][w]; }
    out[65568 + b] = (float)ix;
    v = rv[1][0];
    ix = ri[1][0];
    for (int w = 1; w < 4; ++w)
      if (rv[1][w] > v || (rv[1][w] == v && ri[1][w] < ix)) { v = rv[1][w]; ix = ri[1][w]; }
    out[65576 + b] = (float)ix;
  }
}

extern "C" void kernel_launch(void* const* d_in, const int* in_sizes, int n_in, void* d_out,
                              int out_size, void* d_ws, size_t ws_size, hipStream_t stream) {
  const float* X = (const float*)d_in[0];
  const float* mask = (const float*)d_in[1];
  const float* s_w1 = (const float*)d_in[2];
  const float* s_b1 = (const float*)d_in[3];
  const float* s_g = (const float*)d_in[4];
  const float* s_b = (const float*)d_in[5];
  const float* s_w2 = (const float*)d_in[6];
  const float* s_b2 = (const float*)d_in[7];
  const float* e_w1 = (const float*)d_in[8];
  const float* e_b1 = (const float*)d_in[9];
  const float* e_g = (const float*)d_in[10];
  const float* e_b = (const float*)d_in[11];
  const float* e_w2 = (const float*)d_in[12];
  const float* e_b2 = (const float*)d_in[13];
  const float* t_w1 = (const float*)d_in[14];
  const float* t_b1 = (const float*)d_in[15];
  const float* t_g = (const float*)d_in[16];
  const float* t_b = (const float*)d_in[17];
  const float* t_w2 = (const float*)d_in[18];
  const float* t_b2 = (const float*)d_in[19];

  char* ws = (char*)d_ws;
  _Float16* Xh = (_Float16*)(ws + WS_XH);
  _Float16* Wt = (_Float16*)(ws + WS_WT);
  float* bvec = (float*)(ws + WS_BVEC);
  float* gw2 = (float*)(ws + WS_GW2);
  float* consts = (float*)(ws + WS_CONSTS);
  float* partials = (float*)(ws + WS_PART);
  float* tpart = (float*)(ws + WS_TPART);
  float* out = (float*)d_out;

  k_pre<<<17426, 256, 0, stream>>>(X, Xh, s_w1, e_w1, Wt, s_b1, s_g, s_w2, s_b, s_b2,
                                   e_b1, e_g, e_w2, e_b, e_b2, bvec, gw2, consts);
  k_gemm<<<dim3(16, 128), 512, 0, stream>>>(Xh, Wt, bvec, gw2, partials);
  k_reduce<<<128, 256, 0, stream>>>(partials, consts, mask, out);
  k_type_partial<<<dim3(8, 8), 256, 0, stream>>>(X, t_w1, t_b1, t_g, t_w2, tpart);
  k_type_final<<<1, 256, 0, stream>>>(tpart, t_g, t_b, t_w2, t_b2, out);
  k_band<<<8, 256, 0, stream>>>(out, out);
}

// Round 16
// 395.051 us; speedup vs baseline: 2.2010x; 2.2010x over previous
//
#include <hip/hip_runtime.h>

typedef _Float16 f16x8 __attribute__((ext_vector_type(8)));
typedef float f32x4 __attribute__((ext_vector_type(4)));

#define BIGF 1e30f
#define M_TOT 32768
#define H2 2048

// ---- ws layout (bytes) ----
#define WS_XH 0u                     // 32768*1024 f16 = 67108864
#define WS_WT 67108864u              // 4096*1024 f16  = 8388608
#define WS_BVEC 75497472u            // 4096 f32
#define WS_GW2 75513856u             // 4096 f32
#define WS_CONSTS 75530240u          // 4 f32 (C1s,C2s,C1e,C2e)
#define WS_PART 75530496u            // 16*3*32768 f32 = 6291456
#define WS_TPART 100696320u          // 8*8*6 f32

// ---------------- merged prep: X cvt (16384 blk) + W cvt (1024 blk) + vec/const prep (18 blk) ----
__global__ void k_pre(const float* __restrict__ x, _Float16* __restrict__ xh,
                      const float* __restrict__ w_s, const float* __restrict__ w_e,
                      _Float16* __restrict__ wt,
                      const float* __restrict__ s_b1, const float* __restrict__ s_g,
                      const float* __restrict__ s_w2, const float* __restrict__ s_b,
                      const float* __restrict__ s_b2, const float* __restrict__ e_b1,
                      const float* __restrict__ e_g, const float* __restrict__ e_w2,
                      const float* __restrict__ e_b, const float* __restrict__ e_b2,
                      float* __restrict__ bvec, float* __restrict__ gw2,
                      float* __restrict__ consts) {
  __shared__ float tile[64][65];
  int bid = blockIdx.x;
  if (bid < 16384) {
    size_t i = ((size_t)bid * 256 + threadIdx.x) * 8;
    float4 v0 = *(const float4*)(x + i);
    float4 v1 = *(const float4*)(x + i + 4);
    f16x8 h;
    h[0] = (_Float16)v0.x; h[1] = (_Float16)v0.y; h[2] = (_Float16)v0.z; h[3] = (_Float16)v0.w;
    h[4] = (_Float16)v1.x; h[5] = (_Float16)v1.y; h[6] = (_Float16)v1.z; h[7] = (_Float16)v1.w;
    *(f16x8*)(xh + i) = h;
  } else if (bid < 17408) {
    int r = bid - 16384;
    int bx = r & 31, by = (r >> 5) & 15, bz = r >> 9;
    const float* w = bz ? w_e : w_s;
    int n0 = bx * 64, k0 = by * 64;
    int tx = threadIdx.x & 63, ty = threadIdx.x >> 6;
#pragma unroll
    for (int i = ty; i < 64; i += 4) tile[i][tx] = w[(size_t)(k0 + i) * H2 + n0 + tx];
    __syncthreads();
#pragma unroll
    for (int i = ty; i < 64; i += 4)
      wt[((size_t)(bz * H2 + n0 + i)) * 1024 + k0 + tx] = (_Float16)tile[tx][i];
  } else {
    int blk = bid - 17408;
    if (blk < 16) {
      int i = blk * 256 + threadIdx.x;
      int head = i >> 11, j = i & (H2 - 1);
      bvec[i] = head ? e_b1[j] : s_b1[j];
      gw2[i] = head ? e_g[j] * e_w2[j] : s_g[j] * s_w2[j];
    } else {
      int h = blk - 16;
      const float* g = h ? e_g : s_g;
      const float* b = h ? e_b : s_b;
      const float* w2 = h ? e_w2 : s_w2;
      const float* b2 = h ? e_b2 : s_b2;
      float c1 = 0.f, c2 = 0.f;
      for (int j = threadIdx.x; j < H2; j += 256) {
        float w = w2[j];
        c1 += g[j] * w;
        c2 += b[j] * w;
      }
      for (int m = 1; m < 64; m <<= 1) { c1 += __shfl_xor(c1, m); c2 += __shfl_xor(c2, m); }
      __shared__ float r1[4], r2[4];
      int wid = threadIdx.x >> 6;
      if ((threadIdx.x & 63) == 0) { r1[wid] = c1; r2[wid] = c2; }
      __syncthreads();
      if (threadIdx.x == 0) {
        consts[h * 2 + 0] = r1[0] + r1[1] + r1[2] + r1[3];
        consts[h * 2 + 1] = r2[0] + r2[1] + r2[2] + r2[3] + b2[0];
      }
    }
  }
}

// ---------------- fused GEMM: [32768,1024] x [1024,4096], relu+LN-reduction epilogue ----
// (Round-4/11/14 verified loop — best measured: 298 us, MfmaUtil 42-45%.)
// BM=BN=256, BK=64, 512 threads = 8 waves (2M x 4N), wave tile 128x64, acc[8][4],
// mfma_f32_16x16x32_f16. LDS: 2 x 64KB buffers, XOR-swizzled rows. Phase p issues
// ds_reads for phase p+1 BEFORE the barrier; counted lgkmcnt(4); boundary vmcnt(4)
// at P2. Epilogue cross-wave reduce (4 N-waves share rows) -> 16 partial slices.
#define BUF 65536
#define STA(q, tile, bufo)                                                              \
  __builtin_amdgcn_global_load_lds(                                                     \
      (const __attribute__((address_space(1))) unsigned int*)(srcA + (size_t)(q) * 131072 + (size_t)(tile) * 128), \
      (__attribute__((address_space(3))) unsigned int*)(lds + (bufo) + (q) * 8192 + t * 16), 16, 0, 0)
#define STB(q, tile, bufo)                                                              \
  __builtin_amdgcn_global_load_lds(                                                     \
      (const __attribute__((address_space(1))) unsigned int*)(srcB + (size_t)(q) * 131072 + (size_t)(tile) * 128), \
      (__attribute__((address_space(3))) unsigned int*)(lds + (bufo) + 32768 + (q) * 8192 + t * 16), 16, 0, 0)

#define READA(AF, mi0, BUFO)                                                            \
  AF[0][0] = *(const f16x8*)(lds + (BUFO) + arow + (mi0) * 2048 + low0);                \
  AF[0][1] = *(const f16x8*)(lds + (BUFO) + arow + (mi0) * 2048 + low1);                \
  AF[1][0] = *(const f16x8*)(lds + (BUFO) + arow + ((mi0) + 1) * 2048 + low0);          \
  AF[1][1] = *(const f16x8*)(lds + (BUFO) + arow + ((mi0) + 1) * 2048 + low1);

#define READB(BF, BUFO)                                                                 \
  _Pragma("unroll")                                                                     \
  for (int nj = 0; nj < 4; ++nj) {                                                      \
    BF[nj][0] = *(const f16x8*)(lds + (BUFO) + brow + nj * 2048 + low0);                \
    BF[nj][1] = *(const f16x8*)(lds + (BUFO) + brow + nj * 2048 + low1);                \
  }

#define MFMA2(m0, m1, AF, BF)                                                           \
  __builtin_amdgcn_s_setprio(1);                                                        \
  _Pragma("unroll")                                                                     \
  for (int nj = 0; nj < 4; ++nj) {                                                      \
    acc[m0][nj] = __builtin_amdgcn_mfma_f32_16x16x32_f16(AF[0][0], BF[nj][0], acc[m0][nj], 0, 0, 0); \
    acc[m1][nj] = __builtin_amdgcn_mfma_f32_16x16x32_f16(AF[1][0], BF[nj][0], acc[m1][nj], 0, 0, 0); \
  }                                                                                     \
  _Pragma("unroll")                                                                     \
  for (int nj = 0; nj < 4; ++nj) {                                                      \
    acc[m0][nj] = __builtin_amdgcn_mfma_f32_16x16x32_f16(AF[0][1], BF[nj][1], acc[m0][nj], 0, 0, 0); \
    acc[m1][nj] = __builtin_amdgcn_mfma_f32_16x16x32_f16(AF[1][1], BF[nj][1], acc[m1][nj], 0, 0, 0); \
  }                                                                                     \
  __builtin_amdgcn_s_setprio(0);

#define K_ITER(g, OB, OBN, BFC, BFN)                                                    \
  {                                                                                     \
    /* ---- P0: MFMA chunk0 (afA); prefetch chunk1 -> afB ---- */                       \
    READA(afB, 2, OB);                                                                  \
    if ((g) < 15) { STA(1, (g) + 1, OBN); STA(3, (g) + 1, OBN); }                       \
    asm volatile("s_waitcnt lgkmcnt(4)" ::: "memory");                                  \
    __builtin_amdgcn_s_barrier();                                                       \
    __builtin_amdgcn_sched_barrier(0);                                                  \
    MFMA2(0, 1, afA, BFC);                                                              \
    /* ---- P1: MFMA chunk1 (afB); prefetch chunk2 -> afA ---- */                       \
    READA(afA, 4, OB);                                                                  \
    if ((g) < 14) { STB(0, (g) + 2, OB); STB(1, (g) + 2, OB); }                         \
    asm volatile("s_waitcnt lgkmcnt(4)" ::: "memory");                                  \
    __builtin_amdgcn_s_barrier();                                                       \
    __builtin_amdgcn_sched_barrier(0);                                                  \
    MFMA2(2, 3, afB, BFC);                                                              \
    /* ---- P2: MFMA chunk2 (afA); prefetch chunk3 -> afB; boundary vmcnt ---- */       \
    READA(afB, 6, OB);                                                                  \
    if ((g) < 14) { STB(2, (g) + 2, OB); STB(3, (g) + 2, OB); }                         \
    if ((g) < 14)       asm volatile("s_waitcnt vmcnt(4)" ::: "memory");                \
    else if ((g) == 14) asm volatile("s_waitcnt vmcnt(0)" ::: "memory");                \
    asm volatile("s_waitcnt lgkmcnt(4)" ::: "memory");                                  \
    __builtin_amdgcn_s_barrier();                                                       \
    __builtin_amdgcn_sched_barrier(0);                                                  \
    MFMA2(4, 5, afA, BFC);                                                              \
    /* ---- P3: MFMA chunk3 (afB); prefetch next tile B -> BFN, chunk0 -> afA ---- */   \
    if ((g) < 15) {                                                                     \
      READB(BFN, OBN);                                                                  \
      READA(afA, 0, OBN);                                                               \
      if ((g) < 14) { STA(0, (g) + 2, OB); STA(2, (g) + 2, OB); }                       \
      asm volatile("s_waitcnt lgkmcnt(12)" ::: "memory");                               \
    } else {                                                                            \
      asm volatile("s_waitcnt lgkmcnt(0)" ::: "memory");                                \
    }                                                                                   \
    __builtin_amdgcn_s_barrier();                                                       \
    __builtin_amdgcn_sched_barrier(0);                                                  \
    MFMA2(6, 7, afB, BFC);                                                              \
  }

__global__ __launch_bounds__(512, 2) void k_gemm(const _Float16* __restrict__ Xh,
                                                 const _Float16* __restrict__ Wt,
                                                 const float* __restrict__ bvec,
                                                 const float* __restrict__ gw2,
                                                 float* __restrict__ partials) {
  __shared__ char lds[2 * BUF];  // 128 KiB
  const int nb = blockIdx.x;  // 0..15   (256-col block)
  const int mb = blockIdx.y;  // 0..127  (256-row block)
  const int t = threadIdx.x;
  const int lane = t & 63, wid = t >> 6;
  const int c15 = lane & 15, g4 = lane >> 4;
  const int wmg = wid >> 2;        // 0..1 -> rows wmg*128..+128
  const int wq = wid & 3;          // 0..3 -> cols wq*64..+64
  const int wn = wq * 64;

  f32x4 acc[8][4];
#pragma unroll
  for (int i = 0; i < 8; ++i)
#pragma unroll
    for (int j = 0; j < 4; ++j) acc[i][j] = (f32x4){0.f, 0.f, 0.f, 0.f};

  // stage sources: quarter q (64 rows), thread t writes LDS bytes [t*16, t*16+16)
  const char* Abase = (const char*)(Xh + (size_t)mb * 256 * 1024);
  const char* Bbase = (const char*)(Wt + (size_t)nb * 256 * 1024);
  const int rowl = t >> 3;  // 0..63 row within quarter
  const int swz = ((t & 7) * 16) ^ ((rowl & 7) << 4);
  const char* srcA = Abase + (size_t)rowl * 2048 + swz;
  const char* srcB = Bbase + (size_t)rowl * 2048 + swz;

  // ds_read address pieces
  const int xorv = (c15 & 7) << 4;
  const int low0 = (g4 * 16) ^ xorv;
  const int low1 = (64 + g4 * 16) ^ xorv;
  const int arow = (wmg * 128 + c15) * 128;
  const int brow = 32768 + (wn + c15) * 128;

  // ---- prologue: tile 0 full -> buf0 (8 ops); tile 1 B q0-3 + A q0,q2 -> buf1 (6 ops) ----
  STA(0, 0, 0); STA(1, 0, 0); STA(2, 0, 0); STA(3, 0, 0);
  STB(0, 0, 0); STB(1, 0, 0); STB(2, 0, 0); STB(3, 0, 0);
  STB(0, 1, BUF); STB(1, 1, BUF); STB(2, 1, BUF); STB(3, 1, BUF);
  STA(0, 1, BUF); STA(2, 1, BUF);
  asm volatile("s_waitcnt vmcnt(6)" ::: "memory");
  __builtin_amdgcn_s_barrier();
  __builtin_amdgcn_sched_barrier(0);

  f16x8 afA[2][2], afB[2][2], bfA[4][2], bfB[4][2];
  READB(bfA, 0);
  READA(afA, 0, 0);

#pragma unroll
  for (int gp = 0; gp < 8; ++gp) {
    K_ITER(2 * gp, 0u, BUF, bfA, bfB);
    K_ITER(2 * gp + 1, BUF, 0u, bfB, bfA);
  }

  // ---- epilogue: h = relu(acc + b1); per-lane S1,S2,S3; cross-wave reduce via LDS ----
  __syncthreads();
  float* red = (float*)lds;  // [wmg][wq][row128][3] = 12 KB

  float bv[4], gv[4];
#pragma unroll
  for (int nj = 0; nj < 4; ++nj) {
    int col = nb * 256 + wn + nj * 16 + c15;
    bv[nj] = bvec[col];
    gv[nj] = gw2[col];
  }
#pragma unroll
  for (int mi = 0; mi < 8; ++mi) {
#pragma unroll
    for (int r = 0; r < 4; ++r) {
      float s1 = 0.f, s2 = 0.f, s3 = 0.f;
#pragma unroll
      for (int nj = 0; nj < 4; ++nj) {
        float v = acc[mi][nj][r] + bv[nj];
        v = fmaxf(v, 0.f);
        s1 += v;
        s2 += v * v;
        s3 += v * gv[nj];
      }
#pragma unroll
      for (int m = 1; m < 16; m <<= 1) {
        s1 += __shfl_xor(s1, m);
        s2 += __shfl_xor(s2, m);
        s3 += __shfl_xor(s3, m);
      }
      if (c15 == 0) {
        int row = mi * 16 + g4 * 4 + r;  // 0..127 within wave-group
        float* p = red + (((wmg * 4 + wq) * 128 + row) * 3);
        p[0] = s1; p[1] = s2; p[2] = s3;
      }
    }
  }
  __syncthreads();
  // sum the 4 N-waves; write 16-slice partials
  for (int idx = t; idx < 768; idx += 512) {
    int wmgi = idx / 384;
    int rem = idx - wmgi * 384;
    int row = rem / 3, k = rem - row * 3;
    float s = red[((wmgi * 4 + 0) * 128 + row) * 3 + k] +
              red[((wmgi * 4 + 1) * 128 + row) * 3 + k] +
              red[((wmgi * 4 + 2) * 128 + row) * 3 + k] +
              red[((wmgi * 4 + 3) * 128 + row) * 3 + k];
    int rowg = mb * 256 + wmgi * 128 + row;
    partials[((size_t)(nb * 3 + k)) * M_TOT + rowg] = s;
  }
}

// ---------------- reduce partials (16 slices: 0-7 start, 8-15 end) -> preds ----------------
__global__ void k_reduce(const float* __restrict__ partials, const float* __restrict__ consts,
                         const float* __restrict__ mask, float* __restrict__ out) {
  int m = blockIdx.x * 256 + threadIdx.x;  // 0..32767
  float s1 = 0.f, s2 = 0.f, s3 = 0.f, e1 = 0.f, e2 = 0.f, e3 = 0.f;
  for (int nb = 0; nb < 8; ++nb) {
    s1 += partials[((size_t)(nb * 3 + 0)) * M_TOT + m];
    s2 += partials[((size_t)(nb * 3 + 1)) * M_TOT + m];
    s3 += partials[((size_t)(nb * 3 + 2)) * M_TOT + m];
  }
  for (int nb = 8; nb < 16; ++nb) {
    e1 += partials[((size_t)(nb * 3 + 0)) * M_TOT + m];
    e2 += partials[((size_t)(nb * 3 + 1)) * M_TOT + m];
    e3 += partials[((size_t)(nb * 3 + 2)) * M_TOT + m];
  }
  const float H = (float)H2;
  float mu = s1 / H;
  float var = fmaxf(s2 / H - mu * mu, 0.f);
  float rs = 1.f / sqrtf(var + 1e-12f);
  float score_s = rs * (s3 - mu * consts[0]) + consts[1];
  mu = e1 / H;
  var = fmaxf(e2 / H - mu * mu, 0.f);
  rs = 1.f / sqrtf(var + 1e-12f);
  float score_e = rs * (e3 - mu * consts[2]) + consts[3];
  float mk = BIGF * (1.f - mask[m]);
  out[m] = score_s - mk;
  out[M_TOT + m] = score_e - mk;
}

// ---------------- type head ----------------
__global__ void k_type_partial(const float* __restrict__ X, const float* __restrict__ w1,
                               const float* __restrict__ b1, const float* __restrict__ g,
                               const float* __restrict__ w2, float* __restrict__ tpart) {
  __shared__ float xs[1024];
  int cb = blockIdx.x, tok = blockIdx.y, t = threadIdx.x;
  const float* xp = X + (size_t)tok * 4096 * 1024;  // x[b,0,:]
  for (int i = t; i < 1024; i += 256) xs[i] = xp[i];
  __syncthreads();
  int j = cb * 256 + t;
  float dot = 0.f;
  for (int k = 0; k < 1024; ++k) dot += xs[k] * w1[(size_t)k * H2 + j];
  float h = fmaxf(dot + b1[j], 0.f);
  float gj = g[j];
  float s[6];
  s[0] = h;
  s[1] = h * h;
#pragma unroll
  for (int c = 0; c < 4; ++c) s[2 + c] = h * gj * w2[j * 4 + c];
  for (int m = 1; m < 64; m <<= 1)
#pragma unroll
    for (int q = 0; q < 6; ++q) s[q] += __shfl_xor(s[q], m);
  __shared__ float red[4][6];
  int wid = t >> 6;
  if ((t & 63) == 0)
#pragma unroll
    for (int q = 0; q < 6; ++q) red[wid][q] = s[q];
  __syncthreads();
  if (t == 0)
#pragma unroll
    for (int q = 0; q < 6; ++q)
      tpart[(tok * 8 + cb) * 6 + q] = red[0][q] + red[1][q] + red[2][q] + red[3][q];
}

__global__ void k_type_final(const float* __restrict__ tpart, const float* __restrict__ g,
                             const float* __restrict__ bb, const float* __restrict__ w2,
                             const float* __restrict__ b2, float* __restrict__ out) {
  int t = threadIdx.x;
  float c1[4] = {0.f, 0.f, 0.f, 0.f}, c2[4] = {0.f, 0.f, 0.f, 0.f};
  for (int j = t; j < H2; j += 256) {
    float gj = g[j], bj = bb[j];
#pragma unroll
    for (int c = 0; c < 4; ++c) {
      float w = w2[j * 4 + c];
      c1[c] += gj * w;
      c2[c] += bj * w;
    }
  }
  for (int m = 1; m < 64; m <<= 1)
#pragma unroll
    for (int c = 0; c < 4; ++c) { c1[c] += __shfl_xor(c1[c], m); c2[c] += __shfl_xor(c2[c], m); }
  __shared__ float rC1[4][4], rC2[4][4];
  int wid = t >> 6;
  if ((t & 63) == 0)
#pragma unroll
    for (int c = 0; c < 4; ++c) { rC1[wid][c] = c1[c]; rC2[wid][c] = c2[c]; }
  __syncthreads();
  __shared__ float sC1[4], sC2[4];
  if (t < 4) {
    sC1[t] = rC1[0][t] + rC1[1][t] + rC1[2][t] + rC1[3][t];
    sC2[t] = rC2[0][t] + rC2[1][t] + rC2[2][t] + rC2[3][t];
  }
  __syncthreads();
  if (t < 32) {
    int tok = t >> 2, c = t & 3;
    float s1 = 0.f, s2 = 0.f, s3 = 0.f;
    for (int cb = 0; cb < 8; ++cb) {
      s1 += tpart[(tok * 8 + cb) * 6 + 0];
      s2 += tpart[(tok * 8 + cb) * 6 + 1];
      s3 += tpart[(tok * 8 + cb) * 6 + 2 + c];
    }
    float mu = s1 / (float)H2;
    float var = fmaxf(s2 / (float)H2 - mu * mu, 0.f);
    float rs = 1.f / sqrtf(var + 1e-12f);
    out[65536 + tok * 4 + c] = rs * (s3 - mu * sC1[c]) + sC2[c] + b2[c];
  }
}

// ---------------- band max + argmax ----------------
__global__ void k_band(const float* __restrict__ preds, float* __restrict__ out) {
  __shared__ float ss[4096], se[4096];
  int b = blockIdx.x, t = threadIdx.x;
  for (int i = t; i < 4096; i += 256) {
    ss[i] = preds[(size_t)b * 4096 + i];
    se[i] = preds[M_TOT + (size_t)b * 4096 + i];
  }
  __syncthreads();
  float bv1 = -3.0e38f, bv2 = -3.0e38f;
  int bi1 = 0x7fffffff, bi2 = 0x7fffffff;
  for (int i = t; i < 4096; i += 256) {
    float m1 = -3.0e38f;
    int jmax = i + 15 < 4095 ? i + 15 : 4095;
    for (int j = i; j <= jmax; ++j) m1 = fmaxf(m1, se[j]);
    float v1 = ss[i] + m1;
    if (v1 > bv1 || (v1 == bv1 && i < bi1)) { bv1 = v1; bi1 = i; }
    float m2 = -3.0e38f;
    int imin = i - 15 > 0 ? i - 15 : 0;
    for (int j = imin; j <= i; ++j) m2 = fmaxf(m2, ss[j]);
    float v2 = se[i] + m2;
    if (v2 > bv2 || (v2 == bv2 && i < bi2)) { bv2 = v2; bi2 = i; }
  }
  for (int m = 1; m < 64; m <<= 1) {
    float ov = __shfl_xor(bv1, m);
    int oi = __shfl_xor(bi1, m);
    if (ov > bv1 || (ov == bv1 && oi < bi1)) { bv1 = ov; bi1 = oi; }
    ov = __shfl_xor(bv2, m);
    oi = __shfl_xor(bi2, m);
    if (ov > bv2 || (ov == bv2 && oi < bi2)) { bv2 = ov; bi2 = oi; }
  }
  __shared__ float rv[2][4];
  __shared__ int ri[2][4];
  int wid = t >> 6;
  if ((t & 63) == 0) { rv[0][wid] = bv1; ri[0][wid] = bi1; rv[1][wid] = bv2; ri[1][wid] = bi2; }
  __syncthreads();
  if (t == 0) {
    float v = rv[0][0];
    int ix = ri[0][0];
    for (int w = 1; w < 4; ++w)
      if (rv[0][w] > v || (rv[0][w] == v && ri[0][w] < ix)) { v = rv[0][w]; ix = ri[0][w]; }
    out[65568 + b] = (float)ix;
    v = rv[1][0];
    ix = ri[1][0];
    for (int w = 1; w < 4; ++w)
      if (rv[1][w] > v || (rv[1][w] == v && ri[1][w] < ix)) { v = rv[1][w]; ix = ri[1][w]; }
    out[65576 + b] = (float)ix;
  }
}

extern "C" void kernel_launch(void* const* d_in, const int* in_sizes, int n_in, void* d_out,
                              int out_size, void* d_ws, size_t ws_size, hipStream_t stream) {
  const float* X = (const float*)d_in[0];
  const float* mask = (const float*)d_in[1];
  const float* s_w1 = (const float*)d_in[2];
  const float* s_b1 = (const float*)d_in[3];
  const float* s_g = (const float*)d_in[4];
  const float* s_b = (const float*)d_in[5];
  const float* s_w2 = (const float*)d_in[6];
  const float* s_b2 = (const float*)d_in[7];
  const float* e_w1 = (const float*)d_in[8];
  const float* e_b1 = (const float*)d_in[9];
  const float* e_g = (const float*)d_in[10];
  const float* e_b = (const float*)d_in[11];
  const float* e_w2 = (const float*)d_in[12];
  const float* e_b2 = (const float*)d_in[13];
  const float* t_w1 = (const float*)d_in[14];
  const float* t_b1 = (const float*)d_in[15];
  const float* t_g = (const float*)d_in[16];
  const float* t_b = (const float*)d_in[17];
  const float* t_w2 = (const float*)d_in[18];
  const float* t_b2 = (const float*)d_in[19];

  char* ws = (char*)d_ws;
  _Float16* Xh = (_Float16*)(ws + WS_XH);
  _Float16* Wt = (_Float16*)(ws + WS_WT);
  float* bvec = (float*)(ws + WS_BVEC);
  float* gw2 = (float*)(ws + WS_GW2);
  float* consts = (float*)(ws + WS_CONSTS);
  float* partials = (float*)(ws + WS_PART);
  float* tpart = (float*)(ws + WS_TPART);
  float* out = (float*)d_out;

  k_pre<<<17426, 256, 0, stream>>>(X, Xh, s_w1, e_w1, Wt, s_b1, s_g, s_w2, s_b, s_b2,
                                   e_b1, e_g, e_w2, e_b, e_b2, bvec, gw2, consts);
  k_gemm<<<dim3(16, 128), 512, 0, stream>>>(Xh, Wt, bvec, gw2, partials);
  k_reduce<<<128, 256, 0, stream>>>(partials, consts, mask, out);
  k_type_partial<<<dim3(8, 8), 256, 0, stream>>>(X, t_w1, t_b1, t_g, t_w2, tpart);
  k_type_final<<<1, 256, 0, stream>>>(tpart, t_g, t_b, t_w2, t_b2, out);
  k_band<<<8, 256, 0, stream>>>(out, out);
}

// Round 17
// 389.491 us; speedup vs baseline: 2.2324x; 1.0143x over previous
//
#include <hip/hip_runtime.h>

typedef _Float16 f16x8 __attribute__((ext_vector_type(8)));
typedef float f32x4 __attribute__((ext_vector_type(4)));

#define BIGF 1e30f
#define M_TOT 32768
#define H2 2048

// ---- ws layout (bytes) ----
#define WS_XH 0u                     // 32768*1024 f16 = 67108864
#define WS_WT 67108864u              // 4096*1024 f16  = 8388608
#define WS_BVEC 75497472u            // 4096 f32
#define WS_GW2 75513856u             // 4096 f32
#define WS_CONSTS 75530240u          // 4 f32 (C1s,C2s,C1e,C2e)
#define WS_PART 75530496u            // 16*3*32768 f32 = 6291456
#define WS_TPART 100696320u          // 8*8*6 f32

// ---------------- merged prep: X cvt (16384 blk) + W cvt (1024 blk) + vec/const prep (18 blk) ----
__global__ void k_pre(const float* __restrict__ x, _Float16* __restrict__ xh,
                      const float* __restrict__ w_s, const float* __restrict__ w_e,
                      _Float16* __restrict__ wt,
                      const float* __restrict__ s_b1, const float* __restrict__ s_g,
                      const float* __restrict__ s_w2, const float* __restrict__ s_b,
                      const float* __restrict__ s_b2, const float* __restrict__ e_b1,
                      const float* __restrict__ e_g, const float* __restrict__ e_w2,
                      const float* __restrict__ e_b, const float* __restrict__ e_b2,
                      float* __restrict__ bvec, float* __restrict__ gw2,
                      float* __restrict__ consts) {
  __shared__ float tile[64][65];
  int bid = blockIdx.x;
  if (bid < 16384) {
    size_t i = ((size_t)bid * 256 + threadIdx.x) * 8;
    float4 v0 = *(const float4*)(x + i);
    float4 v1 = *(const float4*)(x + i + 4);
    f16x8 h;
    h[0] = (_Float16)v0.x; h[1] = (_Float16)v0.y; h[2] = (_Float16)v0.z; h[3] = (_Float16)v0.w;
    h[4] = (_Float16)v1.x; h[5] = (_Float16)v1.y; h[6] = (_Float16)v1.z; h[7] = (_Float16)v1.w;
    *(f16x8*)(xh + i) = h;
  } else if (bid < 17408) {
    int r = bid - 16384;
    int bx = r & 31, by = (r >> 5) & 15, bz = r >> 9;
    const float* w = bz ? w_e : w_s;
    int n0 = bx * 64, k0 = by * 64;
    int tx = threadIdx.x & 63, ty = threadIdx.x >> 6;
#pragma unroll
    for (int i = ty; i < 64; i += 4) tile[i][tx] = w[(size_t)(k0 + i) * H2 + n0 + tx];
    __syncthreads();
#pragma unroll
    for (int i = ty; i < 64; i += 4)
      wt[((size_t)(bz * H2 + n0 + i)) * 1024 + k0 + tx] = (_Float16)tile[tx][i];
  } else {
    int blk = bid - 17408;
    if (blk < 16) {
      int i = blk * 256 + threadIdx.x;
      int head = i >> 11, j = i & (H2 - 1);
      bvec[i] = head ? e_b1[j] : s_b1[j];
      gw2[i] = head ? e_g[j] * e_w2[j] : s_g[j] * s_w2[j];
    } else {
      int h = blk - 16;
      const float* g = h ? e_g : s_g;
      const float* b = h ? e_b : s_b;
      const float* w2 = h ? e_w2 : s_w2;
      const float* b2 = h ? e_b2 : s_b2;
      float c1 = 0.f, c2 = 0.f;
      for (int j = threadIdx.x; j < H2; j += 256) {
        float w = w2[j];
        c1 += g[j] * w;
        c2 += b[j] * w;
      }
      for (int m = 1; m < 64; m <<= 1) { c1 += __shfl_xor(c1, m); c2 += __shfl_xor(c2, m); }
      __shared__ float r1[4], r2[4];
      int wid = threadIdx.x >> 6;
      if ((threadIdx.x & 63) == 0) { r1[wid] = c1; r2[wid] = c2; }
      __syncthreads();
      if (threadIdx.x == 0) {
        consts[h * 2 + 0] = r1[0] + r1[1] + r1[2] + r1[3];
        consts[h * 2 + 1] = r2[0] + r2[1] + r2[2] + r2[3] + b2[0];
      }
    }
  }
}

// ---------------- fused GEMM: [32768,1024] x [1024,4096], relu+LN-reduction epilogue ----
// (Round-4/11/14 verified loop — best measured: 298 us, MfmaUtil 42-45%.)
// NEW this round: XCD-bijective block swizzle (2048 blocks, 2048%8==0): 256
// consecutive swizzled blocks (16 A-panels x 16 nb) per XCD -> A-panel L2-local,
// boundary vmcnt loads become L2 hits. Everything else byte-identical.
#define BUF 65536
#define STA(q, tile, bufo)                                                              \
  __builtin_amdgcn_global_load_lds(                                                     \
      (const __attribute__((address_space(1))) unsigned int*)(srcA + (size_t)(q) * 131072 + (size_t)(tile) * 128), \
      (__attribute__((address_space(3))) unsigned int*)(lds + (bufo) + (q) * 8192 + t * 16), 16, 0, 0)
#define STB(q, tile, bufo)                                                              \
  __builtin_amdgcn_global_load_lds(                                                     \
      (const __attribute__((address_space(1))) unsigned int*)(srcB + (size_t)(q) * 131072 + (size_t)(tile) * 128), \
      (__attribute__((address_space(3))) unsigned int*)(lds + (bufo) + 32768 + (q) * 8192 + t * 16), 16, 0, 0)

#define READA(AF, mi0, BUFO)                                                            \
  AF[0][0] = *(const f16x8*)(lds + (BUFO) + arow + (mi0) * 2048 + low0);                \
  AF[0][1] = *(const f16x8*)(lds + (BUFO) + arow + (mi0) * 2048 + low1);                \
  AF[1][0] = *(const f16x8*)(lds + (BUFO) + arow + ((mi0) + 1) * 2048 + low0);          \
  AF[1][1] = *(const f16x8*)(lds + (BUFO) + arow + ((mi0) + 1) * 2048 + low1);

#define READB(BF, BUFO)                                                                 \
  _Pragma("unroll")                                                                     \
  for (int nj = 0; nj < 4; ++nj) {                                                      \
    BF[nj][0] = *(const f16x8*)(lds + (BUFO) + brow + nj * 2048 + low0);                \
    BF[nj][1] = *(const f16x8*)(lds + (BUFO) + brow + nj * 2048 + low1);                \
  }

#define MFMA2(m0, m1, AF, BF)                                                           \
  __builtin_amdgcn_s_setprio(1);                                                        \
  _Pragma("unroll")                                                                     \
  for (int nj = 0; nj < 4; ++nj) {                                                      \
    acc[m0][nj] = __builtin_amdgcn_mfma_f32_16x16x32_f16(AF[0][0], BF[nj][0], acc[m0][nj], 0, 0, 0); \
    acc[m1][nj] = __builtin_amdgcn_mfma_f32_16x16x32_f16(AF[1][0], BF[nj][0], acc[m1][nj], 0, 0, 0); \
  }                                                                                     \
  _Pragma("unroll")                                                                     \
  for (int nj = 0; nj < 4; ++nj) {                                                      \
    acc[m0][nj] = __builtin_amdgcn_mfma_f32_16x16x32_f16(AF[0][1], BF[nj][1], acc[m0][nj], 0, 0, 0); \
    acc[m1][nj] = __builtin_amdgcn_mfma_f32_16x16x32_f16(AF[1][1], BF[nj][1], acc[m1][nj], 0, 0, 0); \
  }                                                                                     \
  __builtin_amdgcn_s_setprio(0);

#define K_ITER(g, OB, OBN, BFC, BFN)                                                    \
  {                                                                                     \
    /* ---- P0: MFMA chunk0 (afA); prefetch chunk1 -> afB ---- */                       \
    READA(afB, 2, OB);                                                                  \
    if ((g) < 15) { STA(1, (g) + 1, OBN); STA(3, (g) + 1, OBN); }                       \
    asm volatile("s_waitcnt lgkmcnt(4)" ::: "memory");                                  \
    __builtin_amdgcn_s_barrier();                                                       \
    __builtin_amdgcn_sched_barrier(0);                                                  \
    MFMA2(0, 1, afA, BFC);                                                              \
    /* ---- P1: MFMA chunk1 (afB); prefetch chunk2 -> afA ---- */                       \
    READA(afA, 4, OB);                                                                  \
    if ((g) < 14) { STB(0, (g) + 2, OB); STB(1, (g) + 2, OB); }                         \
    asm volatile("s_waitcnt lgkmcnt(4)" ::: "memory");                                  \
    __builtin_amdgcn_s_barrier();                                                       \
    __builtin_amdgcn_sched_barrier(0);                                                  \
    MFMA2(2, 3, afB, BFC);                                                              \
    /* ---- P2: MFMA chunk2 (afA); prefetch chunk3 -> afB; boundary vmcnt ---- */       \
    READA(afB, 6, OB);                                                                  \
    if ((g) < 14) { STB(2, (g) + 2, OB); STB(3, (g) + 2, OB); }                         \
    if ((g) < 14)       asm volatile("s_waitcnt vmcnt(4)" ::: "memory");                \
    else if ((g) == 14) asm volatile("s_waitcnt vmcnt(0)" ::: "memory");                \
    asm volatile("s_waitcnt lgkmcnt(4)" ::: "memory");                                  \
    __builtin_amdgcn_s_barrier();                                                       \
    __builtin_amdgcn_sched_barrier(0);                                                  \
    MFMA2(4, 5, afA, BFC);                                                              \
    /* ---- P3: MFMA chunk3 (afB); prefetch next tile B -> BFN, chunk0 -> afA ---- */   \
    if ((g) < 15) {                                                                     \
      READB(BFN, OBN);                                                                  \
      READA(afA, 0, OBN);                                                               \
      if ((g) < 14) { STA(0, (g) + 2, OB); STA(2, (g) + 2, OB); }                       \
      asm volatile("s_waitcnt lgkmcnt(12)" ::: "memory");                               \
    } else {                                                                            \
      asm volatile("s_waitcnt lgkmcnt(0)" ::: "memory");                                \
    }                                                                                   \
    __builtin_amdgcn_s_barrier();                                                       \
    __builtin_amdgcn_sched_barrier(0);                                                  \
    MFMA2(6, 7, afB, BFC);                                                              \
  }

__global__ __launch_bounds__(512, 2) void k_gemm(const _Float16* __restrict__ Xh,
                                                 const _Float16* __restrict__ Wt,
                                                 const float* __restrict__ bvec,
                                                 const float* __restrict__ gw2,
                                                 float* __restrict__ partials) {
  __shared__ char lds[2 * BUF];  // 128 KiB
  // XCD-bijective swizzle: 2048 blocks, XCD x = blocks x*256..x*256+255 (16 mb x 16 nb)
  const int bid = blockIdx.x;
  const int swzb = (bid & 7) * 256 + (bid >> 3);
  const int nb = swzb & 15;   // 0..15  (256-col block)
  const int mb = swzb >> 4;   // 0..127 (256-row block)
  const int t = threadIdx.x;
  const int lane = t & 63, wid = t >> 6;
  const int c15 = lane & 15, g4 = lane >> 4;
  const int wmg = wid >> 2;        // 0..1 -> rows wmg*128..+128
  const int wq = wid & 3;          // 0..3 -> cols wq*64..+64
  const int wn = wq * 64;

  f32x4 acc[8][4];
#pragma unroll
  for (int i = 0; i < 8; ++i)
#pragma unroll
    for (int j = 0; j < 4; ++j) acc[i][j] = (f32x4){0.f, 0.f, 0.f, 0.f};

  // stage sources: quarter q (64 rows), thread t writes LDS bytes [t*16, t*16+16)
  const char* Abase = (const char*)(Xh + (size_t)mb * 256 * 1024);
  const char* Bbase = (const char*)(Wt + (size_t)nb * 256 * 1024);
  const int rowl = t >> 3;  // 0..63 row within quarter
  const int swz = ((t & 7) * 16) ^ ((rowl & 7) << 4);
  const char* srcA = Abase + (size_t)rowl * 2048 + swz;
  const char* srcB = Bbase + (size_t)rowl * 2048 + swz;

  // ds_read address pieces
  const int xorv = (c15 & 7) << 4;
  const int low0 = (g4 * 16) ^ xorv;
  const int low1 = (64 + g4 * 16) ^ xorv;
  const int arow = (wmg * 128 + c15) * 128;
  const int brow = 32768 + (wn + c15) * 128;

  // ---- prologue: tile 0 full -> buf0 (8 ops); tile 1 B q0-3 + A q0,q2 -> buf1 (6 ops) ----
  STA(0, 0, 0); STA(1, 0, 0); STA(2, 0, 0); STA(3, 0, 0);
  STB(0, 0, 0); STB(1, 0, 0); STB(2, 0, 0); STB(3, 0, 0);
  STB(0, 1, BUF); STB(1, 1, BUF); STB(2, 1, BUF); STB(3, 1, BUF);
  STA(0, 1, BUF); STA(2, 1, BUF);
  asm volatile("s_waitcnt vmcnt(6)" ::: "memory");
  __builtin_amdgcn_s_barrier();
  __builtin_amdgcn_sched_barrier(0);

  f16x8 afA[2][2], afB[2][2], bfA[4][2], bfB[4][2];
  READB(bfA, 0);
  READA(afA, 0, 0);

#pragma unroll
  for (int gp = 0; gp < 8; ++gp) {
    K_ITER(2 * gp, 0u, BUF, bfA, bfB);
    K_ITER(2 * gp + 1, BUF, 0u, bfB, bfA);
  }

  // ---- epilogue: h = relu(acc + b1); per-lane S1,S2,S3; cross-wave reduce via LDS ----
  __syncthreads();
  float* red = (float*)lds;  // [wmg][wq][row128][3] = 12 KB

  float bv[4], gv[4];
#pragma unroll
  for (int nj = 0; nj < 4; ++nj) {
    int col = nb * 256 + wn + nj * 16 + c15;
    bv[nj] = bvec[col];
    gv[nj] = gw2[col];
  }
#pragma unroll
  for (int mi = 0; mi < 8; ++mi) {
#pragma unroll
    for (int r = 0; r < 4; ++r) {
      float s1 = 0.f, s2 = 0.f, s3 = 0.f;
#pragma unroll
      for (int nj = 0; nj < 4; ++nj) {
        float v = acc[mi][nj][r] + bv[nj];
        v = fmaxf(v, 0.f);
        s1 += v;
        s2 += v * v;
        s3 += v * gv[nj];
      }
#pragma unroll
      for (int m = 1; m < 16; m <<= 1) {
        s1 += __shfl_xor(s1, m);
        s2 += __shfl_xor(s2, m);
        s3 += __shfl_xor(s3, m);
      }
      if (c15 == 0) {
        int row = mi * 16 + g4 * 4 + r;  // 0..127 within wave-group
        float* p = red + (((wmg * 4 + wq) * 128 + row) * 3);
        p[0] = s1; p[1] = s2; p[2] = s3;
      }
    }
  }
  __syncthreads();
  // sum the 4 N-waves; write 16-slice partials
  for (int idx = t; idx < 768; idx += 512) {
    int wmgi = idx / 384;
    int rem = idx - wmgi * 384;
    int row = rem / 3, k = rem - row * 3;
    float s = red[((wmgi * 4 + 0) * 128 + row) * 3 + k] +
              red[((wmgi * 4 + 1) * 128 + row) * 3 + k] +
              red[((wmgi * 4 + 2) * 128 + row) * 3 + k] +
              red[((wmgi * 4 + 3) * 128 + row) * 3 + k];
    int rowg = mb * 256 + wmgi * 128 + row;
    partials[((size_t)(nb * 3 + k)) * M_TOT + rowg] = s;
  }
}

// ---------------- merged mid: reduce (blk 0-127) + type_partial (blk 128-191) ----------------
__global__ void k_mid(const float* __restrict__ partials, const float* __restrict__ consts,
                      const float* __restrict__ mask, float* __restrict__ out,
                      const float* __restrict__ X, const float* __restrict__ w1,
                      const float* __restrict__ b1, const float* __restrict__ g,
                      const float* __restrict__ w2, float* __restrict__ tpart) {
  __shared__ float xs[1024];
  __shared__ float red[4][6];
  int bid = blockIdx.x, t = threadIdx.x;
  if (bid < 128) {
    int m = bid * 256 + t;  // 0..32767
    float s1 = 0.f, s2 = 0.f, s3 = 0.f, e1 = 0.f, e2 = 0.f, e3 = 0.f;
    for (int nb = 0; nb < 8; ++nb) {
      s1 += partials[((size_t)(nb * 3 + 0)) * M_TOT + m];
      s2 += partials[((size_t)(nb * 3 + 1)) * M_TOT + m];
      s3 += partials[((size_t)(nb * 3 + 2)) * M_TOT + m];
    }
    for (int nb = 8; nb < 16; ++nb) {
      e1 += partials[((size_t)(nb * 3 + 0)) * M_TOT + m];
      e2 += partials[((size_t)(nb * 3 + 1)) * M_TOT + m];
      e3 += partials[((size_t)(nb * 3 + 2)) * M_TOT + m];
    }
    const float H = (float)H2;
    float mu = s1 / H;
    float var = fmaxf(s2 / H - mu * mu, 0.f);
    float rs = 1.f / sqrtf(var + 1e-12f);
    float score_s = rs * (s3 - mu * consts[0]) + consts[1];
    mu = e1 / H;
    var = fmaxf(e2 / H - mu * mu, 0.f);
    rs = 1.f / sqrtf(var + 1e-12f);
    float score_e = rs * (e3 - mu * consts[2]) + consts[3];
    float mk = BIGF * (1.f - mask[m]);
    out[m] = score_s - mk;
    out[M_TOT + m] = score_e - mk;
  } else {
    int r = bid - 128;
    int cb = r & 7, tok = r >> 3;
    const float* xp = X + (size_t)tok * 4096 * 1024;  // x[b,0,:]
    for (int i = t; i < 1024; i += 256) xs[i] = xp[i];
    __syncthreads();
    int j = cb * 256 + t;
    float dot = 0.f;
    for (int k = 0; k < 1024; ++k) dot += xs[k] * w1[(size_t)k * H2 + j];
    float h = fmaxf(dot + b1[j], 0.f);
    float gj = g[j];
    float s[6];
    s[0] = h;
    s[1] = h * h;
#pragma unroll
    for (int c = 0; c < 4; ++c) s[2 + c] = h * gj * w2[j * 4 + c];
    for (int m = 1; m < 64; m <<= 1)
#pragma unroll
      for (int q = 0; q < 6; ++q) s[q] += __shfl_xor(s[q], m);
    int wid = t >> 6;
    if ((t & 63) == 0)
#pragma unroll
      for (int q = 0; q < 6; ++q) red[wid][q] = s[q];
    __syncthreads();
    if (t == 0)
#pragma unroll
      for (int q = 0; q < 6; ++q)
        tpart[(tok * 8 + cb) * 6 + q] = red[0][q] + red[1][q] + red[2][q] + red[3][q];
  }
}

// ---------------- merged fin: type_final (blk 0) + band (blk 1-8) ----------------
__global__ void k_fin(const float* __restrict__ tpart, const float* __restrict__ g,
                      const float* __restrict__ bb, const float* __restrict__ w2,
                      const float* __restrict__ b2, float* __restrict__ out) {
  __shared__ float ss[4096], se[4096];
  __shared__ float rC1[4][4], rC2[4][4];
  __shared__ float sC1[4], sC2[4];
  __shared__ float rv[2][4];
  __shared__ int ri[2][4];
  int bid = blockIdx.x, t = threadIdx.x;
  if (bid == 0) {
    float c1[4] = {0.f, 0.f, 0.f, 0.f}, c2[4] = {0.f, 0.f, 0.f, 0.f};
    for (int j = t; j < H2; j += 256) {
      float gj = g[j], bj = bb[j];
#pragma unroll
      for (int c = 0; c < 4; ++c) {
        float w = w2[j * 4 + c];
        c1[c] += gj * w;
        c2[c] += bj * w;
      }
    }
    for (int m = 1; m < 64; m <<= 1)
#pragma unroll
      for (int c = 0; c < 4; ++c) { c1[c] += __shfl_xor(c1[c], m); c2[c] += __shfl_xor(c2[c], m); }
    int wid = t >> 6;
    if ((t & 63) == 0)
#pragma unroll
      for (int c = 0; c < 4; ++c) { rC1[wid][c] = c1[c]; rC2[wid][c] = c2[c]; }
    __syncthreads();
    if (t < 4) {
      sC1[t] = rC1[0][t] + rC1[1][t] + rC1[2][t] + rC1[3][t];
      sC2[t] = rC2[0][t] + rC2[1][t] + rC2[2][t] + rC2[3][t];
    }
    __syncthreads();
    if (t < 32) {
      int tok = t >> 2, c = t & 3;
      float s1 = 0.f, s2 = 0.f, s3 = 0.f;
      for (int cb = 0; cb < 8; ++cb) {
        s1 += tpart[(tok * 8 + cb) * 6 + 0];
        s2 += tpart[(tok * 8 + cb) * 6 + 1];
        s3 += tpart[(tok * 8 + cb) * 6 + 2 + c];
      }
      float mu = s1 / (float)H2;
      float var = fmaxf(s2 / (float)H2 - mu * mu, 0.f);
      float rs = 1.f / sqrtf(var + 1e-12f);
      out[65536 + tok * 4 + c] = rs * (s3 - mu * sC1[c]) + sC2[c] + b2[c];
    }
  } else {
    int b = bid - 1;
    const float* preds = out;
    for (int i = t; i < 4096; i += 256) {
      ss[i] = preds[(size_t)b * 4096 + i];
      se[i] = preds[M_TOT + (size_t)b * 4096 + i];
    }
    __syncthreads();
    float bv1 = -3.0e38f, bv2 = -3.0e38f;
    int bi1 = 0x7fffffff, bi2 = 0x7fffffff;
    for (int i = t; i < 4096; i += 256) {
      float m1 = -3.0e38f;
      int jmax = i + 15 < 4095 ? i + 15 : 4095;
      for (int j = i; j <= jmax; ++j) m1 = fmaxf(m1, se[j]);
      float v1 = ss[i] + m1;
      if (v1 > bv1 || (v1 == bv1 && i < bi1)) { bv1 = v1; bi1 = i; }
      float m2 = -3.0e38f;
      int imin = i - 15 > 0 ? i - 15 : 0;
      for (int j = imin; j <= i; ++j) m2 = fmaxf(m2, ss[j]);
      float v2 = se[i] + m2;
      if (v2 > bv2 || (v2 == bv2 && i < bi2)) { bv2 = v2; bi2 = i; }
    }
    for (int m = 1; m < 64; m <<= 1) {
      float ov = __shfl_xor(bv1, m);
      int oi = __shfl_xor(bi1, m);
      if (ov > bv1 || (ov == bv1 && oi < bi1)) { bv1 = ov; bi1 = oi; }
      ov = __shfl_xor(bv2, m);
      oi = __shfl_xor(bi2, m);
      if (ov > bv2 || (ov == bv2 && oi < bi2)) { bv2 = ov; bi2 = oi; }
    }
    int wid = t >> 6;
    if ((t & 63) == 0) { rv[0][wid] = bv1; ri[0][wid] = bi1; rv[1][wid] = bv2; ri[1][wid] = bi2; }
    __syncthreads();
    if (t == 0) {
      float v = rv[0][0];
      int ix = ri[0][0];
      for (int w = 1; w < 4; ++w)
        if (rv[0][w] > v || (rv[0][w] == v && ri[0][w] < ix)) { v = rv[0][w]; ix = ri[0][w]; }
      out[65568 + b] = (float)ix;
      v = rv[1][0];
      ix = ri[1][0];
      for (int w = 1; w < 4; ++w)
        if (rv[1][w] > v || (rv[1][w] == v && ri[1][w] < ix)) { v = rv[1][w]; ix = ri[1][w]; }
      out[65576 + b] = (float)ix;
    }
  }
}

extern "C" void kernel_launch(void* const* d_in, const int* in_sizes, int n_in, void* d_out,
                              int out_size, void* d_ws, size_t ws_size, hipStream_t stream) {
  const float* X = (const float*)d_in[0];
  const float* mask = (const float*)d_in[1];
  const float* s_w1 = (const float*)d_in[2];
  const float* s_b1 = (const float*)d_in[3];
  const float* s_g = (const float*)d_in[4];
  const float* s_b = (const float*)d_in[5];
  const float* s_w2 = (const float*)d_in[6];
  const float* s_b2 = (const float*)d_in[7];
  const float* e_w1 = (const float*)d_in[8];
  const float* e_b1 = (const float*)d_in[9];
  const float* e_g = (const float*)d_in[10];
  const float* e_b = (const float*)d_in[11];
  const float* e_w2 = (const float*)d_in[12];
  const float* e_b2 = (const float*)d_in[13];
  const float* t_w1 = (const float*)d_in[14];
  const float* t_b1 = (const float*)d_in[15];
  const float* t_g = (const float*)d_in[16];
  const float* t_b = (const float*)d_in[17];
  const float* t_w2 = (const float*)d_in[18];
  const float* t_b2 = (const float*)d_in[19];

  char* ws = (char*)d_ws;
  _Float16* Xh = (_Float16*)(ws + WS_XH);
  _Float16* Wt = (_Float16*)(ws + WS_WT);
  float* bvec = (float*)(ws + WS_BVEC);
  float* gw2 = (float*)(ws + WS_GW2);
  float* consts = (float*)(ws + WS_CONSTS);
  float* partials = (float*)(ws + WS_PART);
  float* tpart = (float*)(ws + WS_TPART);
  float* out = (float*)d_out;

  k_pre<<<17426, 256, 0, stream>>>(X, Xh, s_w1, e_w1, Wt, s_b1, s_g, s_w2, s_b, s_b2,
                                   e_b1, e_g, e_w2, e_b, e_b2, bvec, gw2, consts);
  k_gemm<<<2048, 512, 0, stream>>>(Xh, Wt, bvec, gw2, partials);
  k_mid<<<192, 256, 0, stream>>>(partials, consts, mask, out, X, t_w1, t_b1, t_g, t_w2, tpart);
  k_fin<<<9, 256, 0, stream>>>(tpart, t_g, t_b, t_w2, t_b2, out);
}